// Round 1
// baseline (112.536 us; speedup 1.0000x reference)
//
#include <hip/hip_runtime.h>

#define B_ 8
#define N_ 1024
#define CIN_ 256
#define COUT_ 512
#define H_ 8
#define DH_ 64

typedef __attribute__((ext_vector_type(8))) short bf8;
typedef __attribute__((ext_vector_type(4))) float f4;

__device__ __forceinline__ short f2bf(float f) {
  unsigned u = __builtin_bit_cast(unsigned, f);
  u += 0x7fffu + ((u >> 16) & 1u);
  return (short)(u >> 16);
}
__device__ __forceinline__ float bf2f(short s) {
  unsigned u = ((unsigned)(unsigned short)s) << 16;
  return __builtin_bit_cast(float, u);
}

#define MFMA16(a, b, c) __builtin_amdgcn_mfma_f32_16x16x32_bf16((a), (b), (c), 0, 0, 0)

// ---- prep: Wt[2048][256] bf16, col-major weight panel (Q|K|V|conv) ----
__global__ void k_build_wt(const float* __restrict__ Wq, const float* __restrict__ Wk,
                           const float* __restrict__ Wv, const float* __restrict__ Cw,
                           short* __restrict__ Wt) {
  int col = blockIdx.x;
  int k = threadIdx.x;
  float v;
  if (col < 512) {
    int h = col >> 6, d = col & 63;
    v = Wq[(h * CIN_ + k) * DH_ + d];
  } else if (col < 1024) {
    int c = col - 512, h = c >> 6, d = c & 63;
    v = Wk[(h * CIN_ + k) * DH_ + d];
  } else if (col < 1536) {
    int c = col - 1024, h = c >> 6, d = c & 63;
    v = Wv[(h * CIN_ + k) * DH_ + d];
  } else {
    v = Cw[(col - 1536) * CIN_ + k];
  }
  Wt[col * CIN_ + k] = f2bf(v);
}

// ---- prep: cast x to bf16 ----
__global__ void k_cast_x(const float* __restrict__ x, short* __restrict__ xb, int n8) {
  int i = blockIdx.x * blockDim.x + threadIdx.x;
  if (i >= n8) return;
  f4 a = *reinterpret_cast<const f4*>(x + (size_t)i * 8);
  f4 b = *reinterpret_cast<const f4*>(x + (size_t)i * 8 + 4);
  bf8 o;
  o[0] = f2bf(a[0]); o[1] = f2bf(a[1]); o[2] = f2bf(a[2]); o[3] = f2bf(a[3]);
  o[4] = f2bf(b[0]); o[5] = f2bf(b[1]); o[6] = f2bf(b[2]); o[7] = f2bf(b[3]);
  *reinterpret_cast<bf8*>(xb + (size_t)i * 8) = o;
}

// ---- GEMM: [8192x256] x [256x2048] -> Q,K,V ([B][H][N][64] bf16) + proj bf16 ----
__global__ __launch_bounds__(256) void k_gemm(const short* __restrict__ xb, const short* __restrict__ Wt,
                                              short* __restrict__ Qw, short* __restrict__ Kw,
                                              short* __restrict__ Vw, short* __restrict__ Pj) {
  __shared__ short Al[128][72];
  __shared__ short Bl[128][72];
  int tid = threadIdx.x;
  int mt = blockIdx.x >> 4, nt = blockIdx.x & 15;
  int row0 = mt * 128, col0 = nt * 128;
  int w = tid >> 6, lane = tid & 63, g = lane >> 4, lr = lane & 15;
  int wm = w >> 1, wn = w & 1;
  f4 acc[4][4];
#pragma unroll
  for (int i = 0; i < 4; ++i)
#pragma unroll
    for (int j = 0; j < 4; ++j) acc[i][j] = (f4){0.f, 0.f, 0.f, 0.f};

  int r_st = tid >> 3, c_st = tid & 7;
  for (int kt = 0; kt < 4; ++kt) {
    int k0 = kt * 64;
#pragma unroll
    for (int i = 0; i < 4; ++i) {
      int r = r_st + i * 32;
      bf8 va = *reinterpret_cast<const bf8*>(xb + (row0 + r) * CIN_ + k0 + c_st * 8);
      bf8 vb = *reinterpret_cast<const bf8*>(Wt + (col0 + r) * CIN_ + k0 + c_st * 8);
      *reinterpret_cast<bf8*>(&Al[r][c_st * 8]) = va;
      *reinterpret_cast<bf8*>(&Bl[r][c_st * 8]) = vb;
    }
    __syncthreads();
    bf8 af[4][2], bb[4][2];
#pragma unroll
    for (int mi = 0; mi < 4; ++mi) {
      af[mi][0] = *reinterpret_cast<const bf8*>(&Al[wm * 64 + mi * 16 + lr][g * 8]);
      af[mi][1] = *reinterpret_cast<const bf8*>(&Al[wm * 64 + mi * 16 + lr][32 + g * 8]);
    }
#pragma unroll
    for (int ni = 0; ni < 4; ++ni) {
      bb[ni][0] = *reinterpret_cast<const bf8*>(&Bl[wn * 64 + ni * 16 + lr][g * 8]);
      bb[ni][1] = *reinterpret_cast<const bf8*>(&Bl[wn * 64 + ni * 16 + lr][32 + g * 8]);
    }
#pragma unroll
    for (int mi = 0; mi < 4; ++mi)
#pragma unroll
      for (int ni = 0; ni < 4; ++ni) {
        acc[mi][ni] = MFMA16(af[mi][0], bb[ni][0], acc[mi][ni]);
        acc[mi][ni] = MFMA16(af[mi][1], bb[ni][1], acc[mi][ni]);
      }
    __syncthreads();
  }
#pragma unroll
  for (int mi = 0; mi < 4; ++mi)
#pragma unroll
    for (int ni = 0; ni < 4; ++ni)
#pragma unroll
      for (int j = 0; j < 4; ++j) {
        int r = row0 + wm * 64 + mi * 16 + g * 4 + j;
        int c = col0 + wn * 64 + ni * 16 + lr;
        short bv = f2bf(acc[mi][ni][j]);
        int b = r >> 10, n = r & 1023;
        if (c < 512) {
          Qw[((b * H_ + (c >> 6)) * N_ + n) * DH_ + (c & 63)] = bv;
        } else if (c < 1024) {
          int cc = c - 512;
          Kw[((b * H_ + (cc >> 6)) * N_ + n) * DH_ + (cc & 63)] = bv;
        } else if (c < 1536) {
          int cc = c - 1024;
          Vw[((b * H_ + (cc >> 6)) * N_ + n) * DH_ + (cc & 63)] = bv;
        } else {
          Pj[r * COUT_ + (c - 1536)] = bv;
        }
      }
}

// ---- flash attention per (b,h,qtile): softmax(QK^T/8)V, relu, store bf16 ----
__global__ __launch_bounds__(256) void k_attn(const short* __restrict__ Qw, const short* __restrict__ Kw,
                                              const short* __restrict__ Vw, short* __restrict__ At) {
  __shared__ short Kl[64][72];
  __shared__ short Vt[64][72];   // transposed V: Vt[dh][kv ^ ((dh>>3)<<3)]
  __shared__ short Pl[4][16][72];
  int tid = threadIdx.x;
  int qt = blockIdx.x & 15;
  int h = (blockIdx.x >> 4) & 7;
  int b = blockIdx.x >> 7;
  const short* Qp = Qw + ((b * H_ + h) * N_) * DH_;
  const short* Kp = Kw + ((b * H_ + h) * N_) * DH_;
  const short* Vp = Vw + ((b * H_ + h) * N_) * DH_;
  int w = tid >> 6, lane = tid & 63, g = lane >> 4, lr = lane & 15;
  int qglob = qt * 64 + w * 16;

  bf8 aq0 = *reinterpret_cast<const bf8*>(Qp + (qglob + lr) * DH_ + g * 8);
  bf8 aq1 = *reinterpret_cast<const bf8*>(Qp + (qglob + lr) * DH_ + 32 + g * 8);

  f4 o[4];
  float m[4], l[4];
#pragma unroll
  for (int i = 0; i < 4; ++i) { o[i] = (f4){0.f, 0.f, 0.f, 0.f}; m[i] = -INFINITY; l[i] = 0.f; }

  int r_st = tid >> 3, c_st = tid & 7;
  const float SC = 0.125f;

  for (int t = 0; t < 16; ++t) {
    __syncthreads();
#pragma unroll
    for (int i = 0; i < 2; ++i) {
      int row = r_st + i * 32;            // kv within tile
      int kvg = t * 64 + row;
      bf8 kv8 = *reinterpret_cast<const bf8*>(Kp + kvg * DH_ + c_st * 8);
      *reinterpret_cast<bf8*>(&Kl[row][c_st * 8]) = kv8;
      bf8 vv8 = *reinterpret_cast<const bf8*>(Vp + kvg * DH_ + c_st * 8);
      int colsw = row ^ (c_st << 3);      // swizzle: conflict-free u16 scatter
#pragma unroll
      for (int jj = 0; jj < 8; ++jj) Vt[c_st * 8 + jj][colsw] = vv8[jj];
    }
    __syncthreads();
    // scores S = (Q K^T) * 1/8
    f4 s[4];
#pragma unroll
    for (int kt = 0; kt < 4; ++kt) {
      bf8 bk0 = *reinterpret_cast<const bf8*>(&Kl[kt * 16 + lr][g * 8]);
      bf8 bk1 = *reinterpret_cast<const bf8*>(&Kl[kt * 16 + lr][32 + g * 8]);
      f4 z = (f4){0.f, 0.f, 0.f, 0.f};
      z = MFMA16(aq0, bk0, z);
      z = MFMA16(aq1, bk1, z);
      s[kt] = z * SC;
    }
    // online softmax (rows live in lane-groups of 16)
    float tm[4], fj[4], rs[4];
#pragma unroll
    for (int j = 0; j < 4; ++j) {
      float v = fmaxf(fmaxf(s[0][j], s[1][j]), fmaxf(s[2][j], s[3][j]));
#pragma unroll
      for (int off = 1; off < 16; off <<= 1) v = fmaxf(v, __shfl_xor(v, off, 16));
      tm[j] = v;
    }
#pragma unroll
    for (int j = 0; j < 4; ++j) {
      float mn = fmaxf(m[j], tm[j]);
      fj[j] = __expf(m[j] - mn);
      m[j] = mn;
      rs[j] = 0.f;
    }
#pragma unroll
    for (int kt = 0; kt < 4; ++kt)
#pragma unroll
      for (int j = 0; j < 4; ++j) {
        float p = __expf(s[kt][j] - m[j]);
        rs[j] += p;
        Pl[w][g * 4 + j][kt * 16 + lr] = f2bf(p);
      }
#pragma unroll
    for (int j = 0; j < 4; ++j) {
#pragma unroll
      for (int off = 1; off < 16; off <<= 1) rs[j] += __shfl_xor(rs[j], off, 16);
      l[j] = l[j] * fj[j] + rs[j];
    }
#pragma unroll
    for (int dt = 0; dt < 4; ++dt) {
      f4 t2 = o[dt];
      t2[0] *= fj[0]; t2[1] *= fj[1]; t2[2] *= fj[2]; t2[3] *= fj[3];
      o[dt] = t2;
    }
    asm volatile("s_waitcnt lgkmcnt(0)" ::: "memory");
    bf8 pa0 = *reinterpret_cast<const bf8*>(&Pl[w][lr][g * 8]);
    bf8 pa1 = *reinterpret_cast<const bf8*>(&Pl[w][lr][32 + g * 8]);
#pragma unroll
    for (int dt = 0; dt < 4; ++dt) {
      int rr = dt * 16 + lr;
      int e = (rr >> 3) & 7;
      bf8 bv0 = *reinterpret_cast<const bf8*>(&Vt[rr][(g * 8) ^ (e << 3)]);
      bf8 bv1 = *reinterpret_cast<const bf8*>(&Vt[rr][(32 + g * 8) ^ (e << 3)]);
      o[dt] = MFMA16(pa0, bv0, o[dt]);
      o[dt] = MFMA16(pa1, bv1, o[dt]);
    }
  }
#pragma unroll
  for (int dt = 0; dt < 4; ++dt)
#pragma unroll
    for (int j = 0; j < 4; ++j) {
      float v = o[dt][j] / l[j];
      v = fmaxf(v, 0.f);
      int n = qt * 64 + w * 16 + g * 4 + j;
      At[(b * N_ + n) * COUT_ + h * DH_ + dt * 16 + lr] = f2bf(v);
    }
}

// ---- add + bias + LayerNorm, f32 out ----
__global__ __launch_bounds__(256) void k_ln(const short* __restrict__ At, const short* __restrict__ Pj,
                                            const float* __restrict__ cb, const float* __restrict__ lw,
                                            const float* __restrict__ lb, float* __restrict__ out) {
  int row = blockIdx.x * 4 + (threadIdx.x >> 6);
  int lane = threadIdx.x & 63;
  int c0 = lane * 8;
  bf8 a8 = *reinterpret_cast<const bf8*>(At + (size_t)row * COUT_ + c0);
  bf8 p8 = *reinterpret_cast<const bf8*>(Pj + (size_t)row * COUT_ + c0);
  float y[8];
  float sum = 0.f, sq = 0.f;
#pragma unroll
  for (int j = 0; j < 8; ++j) {
    float v = bf2f(a8[j]) + bf2f(p8[j]) + cb[c0 + j];
    y[j] = v;
    sum += v;
    sq += v * v;
  }
#pragma unroll
  for (int off = 1; off < 64; off <<= 1) {
    sum += __shfl_xor(sum, off, 64);
    sq += __shfl_xor(sq, off, 64);
  }
  float mean = sum * (1.f / 512.f);
  float var = sq * (1.f / 512.f) - mean * mean;
  float rstd = rsqrtf(var + 1e-5f);
  f4 o0, o1;
#pragma unroll
  for (int j = 0; j < 4; ++j) o0[j] = (y[j] - mean) * rstd * lw[c0 + j] + lb[c0 + j];
#pragma unroll
  for (int j = 0; j < 4; ++j) o1[j] = (y[4 + j] - mean) * rstd * lw[c0 + 4 + j] + lb[c0 + 4 + j];
  *reinterpret_cast<f4*>(out + (size_t)row * COUT_ + c0) = o0;
  *reinterpret_cast<f4*>(out + (size_t)row * COUT_ + c0 + 4) = o1;
}

extern "C" void kernel_launch(void* const* d_in, const int* in_sizes, int n_in,
                              void* d_out, int out_size, void* d_ws, size_t ws_size,
                              hipStream_t stream) {
  const float* x  = (const float*)d_in[0];
  // d_in[1] = adj: dead code in the reference, never read
  const float* Wq = (const float*)d_in[2];
  const float* Wk = (const float*)d_in[3];
  const float* Wv = (const float*)d_in[4];
  const float* Cw = (const float*)d_in[5];
  const float* cb = (const float*)d_in[6];
  const float* lw = (const float*)d_in[7];
  const float* lb = (const float*)d_in[8];
  float* out = (float*)d_out;
  char* ws = (char*)d_ws;
  short* xb = (short*)(ws);                         // 8192*256 bf16      = 4,194,304 B
  short* Wt = (short*)(ws + (size_t)4194304);       // 2048*256 bf16     = 1,048,576 B
  short* Qw = (short*)(ws + (size_t)5242880);       // 8*8*1024*64 bf16  = 8,388,608 B
  short* Kw = (short*)(ws + (size_t)13631488);
  short* Vw = (short*)(ws + (size_t)22020096);
  short* Pj = (short*)(ws + (size_t)30408704);      // 8192*512 bf16
  short* At = (short*)(ws + (size_t)38797312);      // 8192*512 bf16  (end: 47,185,920 B)

  hipLaunchKernelGGL(k_build_wt, dim3(2048), dim3(256), 0, stream, Wq, Wk, Wv, Cw, Wt);
  hipLaunchKernelGGL(k_cast_x, dim3(1024), dim3(256), 0, stream, x, xb, 262144);
  hipLaunchKernelGGL(k_gemm, dim3(1024), dim3(256), 0, stream, xb, Wt, Qw, Kw, Vw, Pj);
  hipLaunchKernelGGL(k_attn, dim3(1024), dim3(256), 0, stream, Qw, Kw, Vw, At);
  hipLaunchKernelGGL(k_ln, dim3(2048), dim3(256), 0, stream, At, Pj, cb, lw, lb, out);
}